// Round 1
// baseline (238.925 us; speedup 1.0000x reference)
//
#include <hip/hip_runtime.h>

// HexPool: out[r, :] = max_{k<7} x[idx[r,k], :], D=64 fp32, idx < N_OUT.
// R5: barrier-free restructure.
//  - Wave-private index staging: lanes 0..55 of each wave load the wave's
//    8 rows x 7 = 56 indices with one coalesced load; __shfl broadcast
//    replaces LDS + __syncthreads (no block-level coupling, no LDS).
//  - 32-bit byte-offset addressing (gather region 41.9 MB < 4 GB):
//    global_load base-SGPR + 32-bit voffset, fewer addr VGPRs/VALU.
//  - __launch_bounds__(256,4): cap VGPR at 128 -> 4 waves/SIMD.

constexpr int N_OUT = 163842;
constexpr int D = 64;
constexpr int K = 7;
constexpr int ROWS_PER_WAVE  = 8;                       // 4 groups x 2 rows
constexpr int WAVES_PER_BLOCK = 4;
constexpr int ROWS_PER_BLOCK = ROWS_PER_WAVE * WAVES_PER_BLOCK;  // 32

typedef float v4f __attribute__((ext_vector_type(4)));

__global__ __launch_bounds__(256, 4) void HexPool_kernel(
    const float* __restrict__ x,
    const int* __restrict__ idx,
    float* __restrict__ out)
{
    const int t    = threadIdx.x;
    const int lane = t & 63;
    const int wave = t >> 6;

    const int blockRow0 = blockIdx.x * ROWS_PER_BLOCK;
    const int waveRow0  = blockRow0 + wave * ROWS_PER_WAVE;

    // Wave-private idx stage: one coalesced load, lanes 0..55.
    // N_OUT*K = 1,146,894 fits int32.
    int myIdx = 0;
    {
        const int gofs = waveRow0 * K + lane;
        if (lane < ROWS_PER_WAVE * K && gofs < N_OUT * K)
            myIdx = idx[gofs];
    }

    const int gw  = (lane >> 4) & 3;   // 16-lane group within wave, 0..3
    const int cgB = (lane & 15) << 4;  // byte offset of this lane's 16B column chunk

    // Broadcast the 14 indices this group's 2 rows need (register-only).
    int j[2][K];
#pragma unroll
    for (int r = 0; r < 2; ++r)
#pragma unroll
        for (int k = 0; k < K; ++k)
            j[r][k] = __shfl(myIdx, (2 * gw + r) * K + k);

    // Issue all 14 gathers back-to-back; 32-bit byte offsets.
    // OOB rows broadcast idx=0 -> safe read of x[0].
    v4f v[2][K];
#pragma unroll
    for (int r = 0; r < 2; ++r)
#pragma unroll
        for (int k = 0; k < K; ++k) {
            const unsigned ofs = ((unsigned)j[r][k] << 8) + (unsigned)cgB;
            v[r][k] = *reinterpret_cast<const v4f*>(
                reinterpret_cast<const char*>(x) + ofs);
        }

#pragma unroll
    for (int r = 0; r < 2; ++r) {
        v4f m = v[r][0];
#pragma unroll
        for (int k = 1; k < K; ++k) {
            m.x = fmaxf(m.x, v[r][k].x);
            m.y = fmaxf(m.y, v[r][k].y);
            m.z = fmaxf(m.z, v[r][k].z);
            m.w = fmaxf(m.w, v[r][k].w);
        }
        const int row = waveRow0 + 2 * gw + r;
        if (row < N_OUT) {
            __builtin_nontemporal_store(
                m, reinterpret_cast<v4f*>(
                       reinterpret_cast<char*>(out) + (((unsigned)row << 8) + (unsigned)cgB)));
        }
    }
}

extern "C" void kernel_launch(void* const* d_in, const int* in_sizes, int n_in,
                              void* d_out, int out_size, void* d_ws, size_t ws_size,
                              hipStream_t stream) {
    const float* x   = (const float*)d_in[0];
    const int*   idx = (const int*)d_in[1];
    float*       out = (float*)d_out;

    const int block = 256;
    const int grid  = (N_OUT + ROWS_PER_BLOCK - 1) / ROWS_PER_BLOCK;  // 5121

    HexPool_kernel<<<grid, block, 0, stream>>>(x, idx, out);
}